// Round 4
// baseline (450.377 us; speedup 1.0000x reference)
//
#include <hip/hip_runtime.h>
#include <hip/hip_bf16.h>

typedef __attribute__((ext_vector_type(8))) short short8;
typedef __attribute__((ext_vector_type(4))) float f32x4;
typedef __attribute__((ext_vector_type(4))) unsigned int u32x4;

__device__ __forceinline__ f32x4 mfma16(short8 a, short8 b, f32x4 c) {
  return __builtin_amdgcn_mfma_f32_16x16x32_bf16(a, b, c, 0, 0, 0);
}

__device__ __forceinline__ void gload_lds16(const void* g, void* l) {
  __builtin_amdgcn_global_load_lds(
      (const __attribute__((address_space(1))) void*)g,
      (__attribute__((address_space(3))) void*)l, 16, 0, 0);
}

__device__ __forceinline__ unsigned int bfp(float lo, float hi) {
  return (unsigned int)__builtin_bit_cast(unsigned short, __float2bfloat16(lo)) |
         ((unsigned int)__builtin_bit_cast(unsigned short, __float2bfloat16(hi)) << 16);
}

__device__ __forceinline__ float b2f(short s) {
  return __builtin_bit_cast(float, ((unsigned int)(unsigned short)s) << 16);
}

// partial-slot offset within a head for qb >= 8 (chunks of 8 tiles)
__device__ __forceinline__ int qoff(int qb) {
  if (qb < 16) return 2 * (qb - 8);
  if (qb < 24) return 16 + 3 * (qb - 16);
  return 40 + 4 * (qb - 24);
}

// ---------------- merged cast fp32 -> bf16 ----------------
struct __align__(8) bh4 { __hip_bfloat16 a, b, c, d; };
struct CastSeg { const float* src; __hip_bfloat16* dst; int n4; };
struct CastArgs { CastSeg seg[7]; int tot4; };

__global__ __launch_bounds__(256) void cast_all(CastArgs a) {
  int i = blockIdx.x * 256 + threadIdx.x;
  const int stride = gridDim.x * 256;
  for (; i < a.tot4; i += stride) {
    int j = i, s = 0;
    while (j >= a.seg[s].n4) { j -= a.seg[s].n4; ++s; }
    float4 v = ((const float4*)a.seg[s].src)[j];
    bh4 o{__float2bfloat16(v.x), __float2bfloat16(v.y),
          __float2bfloat16(v.z), __float2bfloat16(v.w)};
    ((bh4*)a.seg[s].dst)[j] = o;
  }
}

// ---------------- bf16 GEMM, m97 structure: C = A @ B^T ----------------
__global__ __launch_bounds__(256) void gemm_bt(const __hip_bfloat16* __restrict__ A,
                                               const __hip_bfloat16* __restrict__ B,
                                               float* __restrict__ C,
                                               int N, int K) {
  __shared__ __align__(16) __hip_bfloat16 As[128][32];
  __shared__ __align__(16) __hip_bfloat16 Bs[128][32];

  const int tid = threadIdx.x;
  const int lane = tid & 63, wv = tid >> 6;
  const int wm = (wv >> 1) * 64, wn = (wv & 1) * 64;
  const int l15 = lane & 15, g = lane >> 4;
  const int mb = blockIdx.y * 128, nb = blockIdx.x * 128;

  const int srow = wv * 32 + (lane >> 2);
  const int scol = (lane & 3) * 8;
  const __hip_bfloat16* Ap = A + (size_t)(mb + srow) * K + scol;
  const __hip_bfloat16* Bp = B + (size_t)(nb + srow) * K + scol;
  __hip_bfloat16* lA0 = &As[wv * 32][0];
  __hip_bfloat16* lA1 = &As[wv * 32 + 16][0];
  __hip_bfloat16* lB0 = &Bs[wv * 32][0];
  __hip_bfloat16* lB1 = &Bs[wv * 32 + 16][0];

  const f32x4 zf = {0.f, 0.f, 0.f, 0.f};
  f32x4 acc[4][4];
#pragma unroll
  for (int m = 0; m < 4; ++m)
#pragma unroll
    for (int n = 0; n < 4; ++n) acc[m][n] = zf;

  for (int k0 = 0; k0 < K; k0 += 32) {
    __syncthreads();
    gload_lds16(Ap + k0, lA0);
    gload_lds16(Ap + (size_t)16 * K + k0, lA1);
    gload_lds16(Bp + k0, lB0);
    gload_lds16(Bp + (size_t)16 * K + k0, lB1);
    __syncthreads();
    short8 af[4], bf[4];
#pragma unroll
    for (int m = 0; m < 4; ++m) af[m] = *(const short8*)&As[wm + m * 16 + l15][g * 8];
#pragma unroll
    for (int n = 0; n < 4; ++n) bf[n] = *(const short8*)&Bs[wn + n * 16 + l15][g * 8];
#pragma unroll
    for (int m = 0; m < 4; ++m)
#pragma unroll
      for (int n = 0; n < 4; ++n) acc[m][n] = mfma16(af[m], bf[n], acc[m][n]);
  }

#pragma unroll
  for (int m = 0; m < 4; ++m)
#pragma unroll
    for (int n = 0; n < 4; ++n)
#pragma unroll
      for (int r = 0; r < 4; ++r)
        C[(size_t)(mb + wm + m * 16 + g * 4 + r) * N + (nb + wn + n * 16 + l15)] =
            acc[m][n][r];
}

// ---------------- post-process: RMSNorm + RoPE + layout changes ----------------
__global__ __launch_bounds__(256) void postproc(const float* __restrict__ C1,
                                                const float* __restrict__ qw,
                                                const float* __restrict__ kw,
                                                __hip_bfloat16* __restrict__ qn,
                                                __hip_bfloat16* __restrict__ kn,
                                                __hip_bfloat16* __restrict__ vt,
                                                __hip_bfloat16* __restrict__ rq,
                                                __hip_bfloat16* __restrict__ rk) {
  constexpr int S = 2048;
  const int s = blockIdx.x;
  const int tid = threadIdx.x;
  const int lane = tid & 63;
  const int wv = tid >> 6;
  const float* row = C1 + (size_t)s * 3840;

  const float f = exp2f(-(float)lane * (13.287712379549449f / 64.0f));
  const float ang = (float)s * f;
  float sn, cs;
  sincosf(ang, &sn, &cs);

  for (int hr = wv; hr < 20; hr += 4) {
    const float* base;
    __hip_bfloat16* dst;
    const float* nw;
    float oscale;
    if (hr < 16) {
      base = row + hr * 128;
      dst = qn + ((size_t)hr * S + s) * 128;
      nw = qw;
      oscale = 0.08838834764831845f;  // 1/sqrt(128) folded into q
    } else {
      const int h4 = hr - 16;
      base = row + 2048 + h4 * 128;
      dst = kn + ((size_t)h4 * S + s) * 128;
      nw = kw;
      oscale = 1.0f;
    }
    const float x1 = base[lane], x2 = base[lane + 64];
    float ss = x1 * x1 + x2 * x2;
#pragma unroll
    for (int mk = 1; mk < 64; mk <<= 1) ss += __shfl_xor(ss, mk);
    const float rms = rsqrtf(ss * (1.0f / 128.0f) + 1e-6f);
    const float x1n = x1 * rms * nw[lane];
    const float x2n = x2 * rms * nw[lane + 64];
    dst[lane]      = __float2bfloat16((x1n * cs - x2n * sn) * oscale);
    dst[lane + 64] = __float2bfloat16((x2n * cs + x1n * sn) * oscale);
  }
  for (int i = tid; i < 512; i += 256) {
    const int h4 = i >> 7, d = i & 127;
    vt[((size_t)h4 * 128 + d) * S + s] = __float2bfloat16(row[2560 + i]);
  }
  for (int i = tid; i < 768; i += 256) {
    if (i < 384) {
      rq[((size_t)(i >> 5) * S + s) * 32 + (i & 31)] = __float2bfloat16(row[3072 + i]);
    } else {
      const int j = i - 384;
      rk[((size_t)(j >> 5) * S + s) * 32 + (j & 31)] = __float2bfloat16(row[3072 + i]);
    }
  }
}

// ---------------- flash attention, KV-split, swapped-QK, no P-LDS ----------------
// grid 1280. Mapping (heavy-first): h = bid&15, u = bid>>4 in [0,80):
//   u<32: qb=31-(u>>2), s=u&3 | u<56: v=u-32, qb=23-v/3, s=v%3
//   u<72: v=u-56, qb=15-(v>>1), s=v&1 | else qb=7-(u-72), s=0
// Block: 4 waves x 16 q-rows. KV tile 64, single-buffer swizzled LDS (32KB).
// Swapped QK^T: lane holds P[t=tf*16+g*4+r][q=l15]; P->A-frag via shfl.
// qb<=7: direct write. Else pre-divided partial O (bf16) + l (fp32) per slot.
__global__ __launch_bounds__(256, 3) void attn_kernel(
    const __hip_bfloat16* __restrict__ qn, const __hip_bfloat16* __restrict__ kn,
    const __hip_bfloat16* __restrict__ vt, const __hip_bfloat16* __restrict__ rq,
    const __hip_bfloat16* __restrict__ rk, const float* __restrict__ gsc,
    __hip_bfloat16* __restrict__ ao, __hip_bfloat16* __restrict__ pO,
    float* __restrict__ pL) {
  constexpr int S = 2048;
  constexpr float L2E = 1.4426950408889634f;
  const int bid = blockIdx.x;
  const int h = bid & 15;
  const int u = bid >> 4;
  int qb, sp;
  if (u < 32)      { qb = 31 - (u >> 2); sp = u & 3; }
  else if (u < 56) { int v = u - 32; qb = 23 - v / 3; sp = v % 3; }
  else if (u < 72) { int v = u - 56; qb = 15 - (v >> 1); sp = v & 1; }
  else             { qb = 7 - (u - 72); sp = 0; }

  const int tid = threadIdx.x;
  const int lane = tid & 63;
  const int wv = tid >> 6;
  const int qs = qb * 64 + wv * 16;
  const int l15 = lane & 15, g = lane >> 4;
  const int h4 = h >> 2;
  const bool has_bias = (h < 12);
  const bool symh = (h < 4);
  const float gs = has_bias ? gsc[h] : 0.0f;
  const f32x4 zf = {0.f, 0.f, 0.f, 0.f};

  const int nt = qb + 1;
  const int t0 = sp * 8;
  const int t1 = (t0 + 8 < nt) ? t0 + 8 : nt;

  // K [64][128] bf16 + V [128][64] bf16, single buffer, XOR-swizzled rows.
  __shared__ __align__(16) char KsRaw[16384];
  __shared__ __align__(16) char VsRaw[16384];

  const int sxk = ((tid >> 4) & 7) << 4;
  const int sxv = ((tid >> 3) & 7) << 4;
  const int k_wr = (tid * 16) ^ sxk;
  const int v_wr = (tid * 16) ^ sxv;
  const int kx = (l15 & 7) << 4;

  // Q fragments (B-operand: col=q=l15, k=g*8+j)
  short8 qf[4];
  {
    const __hip_bfloat16* qrow = qn + ((size_t)h * S + qs + l15) * 128 + g * 8;
#pragma unroll
    for (int kc = 0; kc < 4; ++kc) qf[kc] = *(const short8*)(qrow + kc * 32);
  }
  short8 rqA = {}, rkA = {};
  if (has_bias) rqA = *(const short8*)(rq + ((size_t)h * S + qs + l15) * 32 + g * 8);
  if (symh)     rkA = *(const short8*)(rk + ((size_t)h * S + qs + l15) * 32 + g * 8);

  float lp = 0.0f;  // per-lane partial row-sum for q = qs + l15
  f32x4 acc[8];
#pragma unroll
  for (int fb = 0; fb < 8; ++fb) acc[fb] = zf;

  // prologue: global loads for tile t0; bias A-frags for tile t0
  short8 kreg[4], vreg[4];
#pragma unroll
  for (int c = 0; c < 4; ++c) {
    kreg[c] = *(const short8*)(kn + ((size_t)(h4 * S + t0 * 64 + c * 16 + (tid >> 4))) * 128 + (tid & 15) * 8);
    vreg[c] = *(const short8*)(vt + ((size_t)(h4 * 128 + c * 32 + (tid >> 3))) * S + t0 * 64 + (tid & 7) * 8);
  }
  short8 rkB[4], rqB[4];
  if (has_bias) {
#pragma unroll
    for (int tf = 0; tf < 4; ++tf)
      rkB[tf] = *(const short8*)(rk + ((size_t)h * S + t0 * 64 + tf * 16 + l15) * 32 + g * 8);
    if (symh) {
#pragma unroll
      for (int tf = 0; tf < 4; ++tf)
        rqB[tf] = *(const short8*)(rq + ((size_t)h * S + t0 * 64 + tf * 16 + l15) * 32 + g * 8);
    }
  }

  const int srcA = l15 + ((g & 1) << 5);
  const int srcB = srcA + 16;
  const bool ghi = (g >= 2);

  for (int t = t0; t < t1; ++t) {
    const int tbase = t * 64;
    // stage tile t (regs -> LDS), then issue t+1 global loads
#pragma unroll
    for (int c = 0; c < 4; ++c) {
      *(short8*)(&KsRaw[c * 4096 + k_wr]) = kreg[c];
      *(short8*)(&VsRaw[c * 4096 + v_wr]) = vreg[c];
    }
    if (t + 1 < t1) {
      const int tb2 = tbase + 64;
#pragma unroll
      for (int c = 0; c < 4; ++c) {
        kreg[c] = *(const short8*)(kn + ((size_t)(h4 * S + tb2 + c * 16 + (tid >> 4))) * 128 + (tid & 15) * 8);
        vreg[c] = *(const short8*)(vt + ((size_t)(h4 * 128 + c * 32 + (tid >> 3))) * S + tb2 + (tid & 7) * 8);
      }
    }
    __syncthreads();  // staged tile visible

    // bias (swapped): bias^T[t][q]
    f32x4 bias4[4];
    if (has_bias) {
#pragma unroll
      for (int tf = 0; tf < 4; ++tf) bias4[tf] = mfma16(rkB[tf], rqA, zf);
      if (symh) {
#pragma unroll
        for (int tf = 0; tf < 4; ++tf) {
          f32x4 b2 = mfma16(rqB[tf], rkA, zf);
#pragma unroll
          for (int r = 0; r < 4; ++r) bias4[tf][r] = 0.5f * (bias4[tf][r] + b2[r]);
        }
      }
      if (t + 1 < t1) {  // prefetch next tile's bias A-frags
        const int tb2 = tbase + 64;
#pragma unroll
        for (int tf = 0; tf < 4; ++tf)
          rkB[tf] = *(const short8*)(rk + ((size_t)h * S + tb2 + tf * 16 + l15) * 32 + g * 8);
        if (symh) {
#pragma unroll
          for (int tf = 0; tf < 4; ++tf)
            rqB[tf] = *(const short8*)(rq + ((size_t)h * S + tb2 + tf * 16 + l15) * 32 + g * 8);
        }
      }
    }

    // swapped QK^T: C[t'][q], rows t' = tf*16+g*4+r, col q = l15
    f32x4 sc[4];
#pragma unroll
    for (int tf = 0; tf < 4; ++tf) {
      f32x4 s4 = zf;
#pragma unroll
      for (int kc = 0; kc < 4; ++kc) {
        short8 kf = *(const short8*)(&KsRaw[((((tf * 16 + l15) << 8) + (kc << 6) + (g << 4)) ^ kx)]);
        s4 = mfma16(kf, qf[kc], s4);
      }
#pragma unroll
      for (int r = 0; r < 4; ++r) {
        float sv = s4[r];
        if (has_bias) sv += gs * bias4[tf][r];
        if (tbase + tf * 16 + g * 4 + r > qs + l15) sv = -1e30f;
        const float p = exp2f(sv * L2E);
        lp += p;
        sc[tf][r] = p;
      }
    }

    // P (C-frag, [t][q]) -> PV A-frag ([q][t]) in-register via shfl
    unsigned int pk0[4], pk1[4];
#pragma unroll
    for (int tf = 0; tf < 4; ++tf) {
      pk0[tf] = bfp(sc[tf][0], sc[tf][1]);
      pk1[tf] = bfp(sc[tf][2], sc[tf][3]);
    }
    unsigned int a0[4], a1[4], b0[4], b1[4];
#pragma unroll
    for (int tf = 0; tf < 4; ++tf) {
      a0[tf] = __shfl(pk0[tf], srcA);
      a1[tf] = __shfl(pk1[tf], srcA);
      b0[tf] = __shfl(pk0[tf], srcB);
      b1[tf] = __shfl(pk1[tf], srcB);
    }
    u32x4 w0 = {ghi ? a0[1] : a0[0], ghi ? a1[1] : a1[0],
                ghi ? b0[1] : b0[0], ghi ? b1[1] : b1[0]};
    u32x4 w1 = {ghi ? a0[3] : a0[2], ghi ? a1[3] : a1[2],
                ghi ? b0[3] : b0[2], ghi ? b1[3] : b1[2]};
    const short8 pa0 = __builtin_bit_cast(short8, w0);
    const short8 pa1 = __builtin_bit_cast(short8, w1);

#pragma unroll
    for (int fb = 0; fb < 8; ++fb) {
      short8 v0 = *(const short8*)(&VsRaw[((((fb * 16 + l15) << 7) + (g << 4)) ^ kx)]);
      short8 v1 = *(const short8*)(&VsRaw[((((fb * 16 + l15) << 7) + 64 + (g << 4)) ^ kx)]);
      acc[fb] = mfma16(pa0, v0, acc[fb]);
      acc[fb] = mfma16(pa1, v1, acc[fb]);
    }
    __syncthreads();  // all waves done reading LDS before next overwrite
  }

  // total l for q = l15 (sum over the 4 g-groups), then per-row inverse
  float lt = lp;
  lt += __shfl_xor(lt, 16);
  lt += __shfl_xor(lt, 32);
  const float linv = 1.0f / lt;
  float lr[4];
#pragma unroll
  for (int r = 0; r < 4; ++r) lr[r] = __shfl(linv, g * 4 + r);

  if (qb <= 7) {
#pragma unroll
    for (int fb = 0; fb < 8; ++fb)
#pragma unroll
      for (int r = 0; r < 4; ++r) {
        const int srow = qs + g * 4 + r;
        ao[(size_t)srow * 2048 + h * 128 + fb * 16 + l15] =
            __float2bfloat16(acc[fb][r] * lr[r]);
      }
  } else {
    const int slot = h * 72 + qoff(qb) + sp;
#pragma unroll
    for (int fb = 0; fb < 8; ++fb)
#pragma unroll
      for (int r = 0; r < 4; ++r) {
        pO[(size_t)slot * 8192 + (wv * 16 + g * 4 + r) * 128 + fb * 16 + l15] =
            __float2bfloat16(acc[fb][r] * lr[r]);
      }
    if (g == 0) pL[slot * 64 + wv * 16 + l15] = lt;
  }
}

// ---------------- combine partial attention outputs ----------------
// grid 384: h = idx&15, qb = 8 + (idx>>4). O = sum(l_s * O_s) / sum(l_s).
__global__ __launch_bounds__(256) void attn_combine(const __hip_bfloat16* __restrict__ pO,
                                                    const float* __restrict__ pL,
                                                    __hip_bfloat16* __restrict__ ao) {
  const int idx = blockIdx.x;
  const int h = idx & 15;
  const int qb = 8 + (idx >> 4);
  const int nsplit = (qb + 8) >> 3;
  const int slot0 = h * 72 + qoff(qb);
  const int tid = threadIdx.x;

  __shared__ float Lw[4][64];
  __shared__ float Li[64];
  if (tid < 64) {
    float tot = 0.0f;
    for (int s = 0; s < nsplit; ++s) {
      const float w = pL[(slot0 + s) * 64 + tid];
      Lw[s][tid] = w;
      tot += w;
    }
    Li[tid] = 1.0f / tot;
  }
  __syncthreads();

  for (int j = tid; j < 1024; j += 256) {
    const int row = j >> 4;
    const int cv = (j & 15) * 8;
    float s8[8] = {0, 0, 0, 0, 0, 0, 0, 0};
    for (int s = 0; s < nsplit; ++s) {
      const short8 o = *(const short8*)(pO + (size_t)(slot0 + s) * 8192 + row * 128 + cv);
      const float w = Lw[s][row];
#pragma unroll
      for (int e = 0; e < 8; ++e) s8[e] += w * b2f(o[e]);
    }
    const float inv = Li[row];
    short8 ov;
#pragma unroll
    for (int e = 0; e < 8; ++e)
      ov[e] = (short)__builtin_bit_cast(unsigned short, __float2bfloat16(s8[e] * inv));
    *(short8*)(ao + (size_t)(qb * 64 + row) * 2048 + h * 128 + cv) = ov;
  }
}

// ---------------- launch ----------------
extern "C" void kernel_launch(void* const* d_in, const int* in_sizes, int n_in,
                              void* d_out, int out_size, void* d_ws, size_t ws_size,
                              hipStream_t stream) {
  (void)in_sizes; (void)n_in; (void)out_size; (void)ws_size;
  constexpr int S = 2048, E = 2048;

  const float* x   = (const float*)d_in[0];
  const float* Wq  = (const float*)d_in[1];
  const float* Wk  = (const float*)d_in[2];
  const float* Wv  = (const float*)d_in[3];
  const float* Wo  = (const float*)d_in[4];
  const float* qw  = (const float*)d_in[5];
  const float* kw  = (const float*)d_in[6];
  const float* Wrq = (const float*)d_in[7];
  const float* Wrk = (const float*)d_in[8];
  const float* gsc = (const float*)d_in[9];
  float* out = (float*)d_out;

  char* ws = (char*)d_ws;
  size_t off = 0;
  auto alloc = [&](size_t bytes) -> void* {
    void* p = ws + off;
    off += (bytes + 255) & ~(size_t)255;
    return p;
  };
  __hip_bfloat16* xb   = (__hip_bfloat16*)alloc((size_t)S * E * 2);
  __hip_bfloat16* Wall = (__hip_bfloat16*)alloc((size_t)3840 * E * 2);
  __hip_bfloat16* Wob  = (__hip_bfloat16*)alloc((size_t)E * E * 2);
  __hip_bfloat16* qnb  = (__hip_bfloat16*)alloc((size_t)16 * S * 128 * 2);
  __hip_bfloat16* knb  = (__hip_bfloat16*)alloc((size_t)4 * S * 128 * 2);
  __hip_bfloat16* vtb  = (__hip_bfloat16*)alloc((size_t)4 * 128 * S * 2);
  __hip_bfloat16* rqb  = (__hip_bfloat16*)alloc((size_t)12 * S * 32 * 2);
  __hip_bfloat16* rkb  = (__hip_bfloat16*)alloc((size_t)12 * S * 32 * 2);
  float* C1            = (float*)alloc((size_t)S * 3840 * 4);
  __hip_bfloat16* ao   = (__hip_bfloat16*)C1;  // overlay: C1 dead after postproc

  // partial buffers overlay the xb+Wall region (dead after gemm1/postproc):
  // pO: 1152 slots x 64 x 128 bf16 = 18,874,368 B; pL: 1152 x 64 f32 = 294,912 B.
  __hip_bfloat16* pO = (__hip_bfloat16*)ws;
  float* pL = (float*)(ws + 18874368);

  CastArgs ca;
  ca.seg[0] = {x,   xb,                      (int)((size_t)S * E / 4)};
  ca.seg[1] = {Wq,  Wall,                    (int)((size_t)E * E / 4)};
  ca.seg[2] = {Wk,  Wall + (size_t)2048 * E, (int)((size_t)512 * E / 4)};
  ca.seg[3] = {Wv,  Wall + (size_t)2560 * E, (int)((size_t)512 * E / 4)};
  ca.seg[4] = {Wrq, Wall + (size_t)3072 * E, (int)((size_t)384 * E / 4)};
  ca.seg[5] = {Wrk, Wall + (size_t)3456 * E, (int)((size_t)384 * E / 4)};
  ca.seg[6] = {Wo,  Wob,                     (int)((size_t)E * E / 4)};
  ca.tot4 = 0;
  for (int i = 0; i < 7; ++i) ca.tot4 += ca.seg[i].n4;
  cast_all<<<dim3(2048), dim3(256), 0, stream>>>(ca);

  gemm_bt<<<dim3(30, 16), dim3(256), 0, stream>>>(xb, Wall, C1, 3840, E);
  postproc<<<dim3(2048), dim3(256), 0, stream>>>(C1, qw, kw, qnb, knb, vtb, rqb, rkb);
  attn_kernel<<<dim3(1280), dim3(256), 0, stream>>>(qnb, knb, vtb, rqb, rkb, gsc,
                                                    ao, pO, pL);
  attn_combine<<<dim3(384), dim3(256), 0, stream>>>(pO, pL, ao);
  gemm_bt<<<dim3(16, 16), dim3(256), 0, stream>>>(ao, Wob, out, E, E);
}

// Round 6
// 359.236 us; speedup vs baseline: 1.2537x; 1.2537x over previous
//
#include <hip/hip_runtime.h>
#include <hip/hip_bf16.h>

typedef __attribute__((ext_vector_type(8))) short short8;
typedef __attribute__((ext_vector_type(4))) float f32x4;
typedef __attribute__((ext_vector_type(4))) unsigned int u32x4;

__device__ __forceinline__ f32x4 mfma16(short8 a, short8 b, f32x4 c) {
  return __builtin_amdgcn_mfma_f32_16x16x32_bf16(a, b, c, 0, 0, 0);
}

__device__ __forceinline__ void gload_lds16(const void* g, void* l) {
  __builtin_amdgcn_global_load_lds(
      (const __attribute__((address_space(1))) void*)g,
      (__attribute__((address_space(3))) void*)l, 16, 0, 0);
}

__device__ __forceinline__ unsigned int bfp(float lo, float hi) {
  return (unsigned int)__builtin_bit_cast(unsigned short, __float2bfloat16(lo)) |
         ((unsigned int)__builtin_bit_cast(unsigned short, __float2bfloat16(hi)) << 16);
}

// ---------------- merged cast fp32 -> bf16 ----------------
struct __align__(8) bh4 { __hip_bfloat16 a, b, c, d; };
struct CastSeg { const float* src; __hip_bfloat16* dst; int n4; };
struct CastArgs { CastSeg seg[7]; int tot4; };

__global__ __launch_bounds__(256) void cast_all(CastArgs a) {
  int i = blockIdx.x * 256 + threadIdx.x;
  const int stride = gridDim.x * 256;
  for (; i < a.tot4; i += stride) {
    int j = i, s = 0;
    while (j >= a.seg[s].n4) { j -= a.seg[s].n4; ++s; }
    float4 v = ((const float4*)a.seg[s].src)[j];
    bh4 o{__float2bfloat16(v.x), __float2bfloat16(v.y),
          __float2bfloat16(v.z), __float2bfloat16(v.w)};
    ((bh4*)a.seg[s].dst)[j] = o;
  }
}

// ---------------- bf16 GEMM, m97 structure, BM=64 x BN=128: C = A @ B^T ----------
// 4 waves; wave owns 64x32 of C (wn = wv*32). Linear LDS + global_load_lds.
__global__ __launch_bounds__(256) void gemm_bt(const __hip_bfloat16* __restrict__ A,
                                               const __hip_bfloat16* __restrict__ B,
                                               float* __restrict__ C,
                                               int N, int K) {
  __shared__ __align__(16) __hip_bfloat16 As[64][32];
  __shared__ __align__(16) __hip_bfloat16 Bs[128][32];

  const int tid = threadIdx.x;
  const int lane = tid & 63, wv = tid >> 6;
  const int wn = wv * 32;
  const int l15 = lane & 15, g = lane >> 4;
  const int mb = blockIdx.y * 64, nb = blockIdx.x * 128;

  const int arow = wv * 16 + (lane >> 2);
  const int brow = wv * 32 + (lane >> 2);
  const int scol = (lane & 3) * 8;
  const __hip_bfloat16* Ap = A + (size_t)(mb + arow) * K + scol;
  const __hip_bfloat16* Bp = B + (size_t)(nb + brow) * K + scol;
  __hip_bfloat16* lA  = &As[wv * 16][0];
  __hip_bfloat16* lB0 = &Bs[wv * 32][0];
  __hip_bfloat16* lB1 = &Bs[wv * 32 + 16][0];

  const f32x4 zf = {0.f, 0.f, 0.f, 0.f};
  f32x4 acc[4][2];
#pragma unroll
  for (int m = 0; m < 4; ++m)
#pragma unroll
    for (int n = 0; n < 2; ++n) acc[m][n] = zf;

  for (int k0 = 0; k0 < K; k0 += 32) {
    __syncthreads();
    gload_lds16(Ap + k0, lA);
    gload_lds16(Bp + k0, lB0);
    gload_lds16(Bp + (size_t)16 * K + k0, lB1);
    __syncthreads();
    short8 af[4], bf[2];
#pragma unroll
    for (int m = 0; m < 4; ++m) af[m] = *(const short8*)&As[m * 16 + l15][g * 8];
#pragma unroll
    for (int n = 0; n < 2; ++n) bf[n] = *(const short8*)&Bs[wn + n * 16 + l15][g * 8];
#pragma unroll
    for (int m = 0; m < 4; ++m)
#pragma unroll
      for (int n = 0; n < 2; ++n) acc[m][n] = mfma16(af[m], bf[n], acc[m][n]);
  }

#pragma unroll
  for (int m = 0; m < 4; ++m)
#pragma unroll
    for (int n = 0; n < 2; ++n)
#pragma unroll
      for (int r = 0; r < 4; ++r)
        C[(size_t)(mb + m * 16 + g * 4 + r) * N + (nb + wn + n * 16 + l15)] =
            acc[m][n][r];
}

// ---------------- post-process: RMSNorm + RoPE + layout changes ----------------
__global__ __launch_bounds__(256) void postproc(const float* __restrict__ C1,
                                                const float* __restrict__ qw,
                                                const float* __restrict__ kw,
                                                __hip_bfloat16* __restrict__ qn,
                                                __hip_bfloat16* __restrict__ kn,
                                                __hip_bfloat16* __restrict__ vt,
                                                __hip_bfloat16* __restrict__ rq,
                                                __hip_bfloat16* __restrict__ rk) {
  constexpr int S = 2048;
  const int s = blockIdx.x;
  const int tid = threadIdx.x;
  const int lane = tid & 63;
  const int wv = tid >> 6;
  const float* row = C1 + (size_t)s * 3840;

  const float f = exp2f(-(float)lane * (13.287712379549449f / 64.0f));
  const float ang = (float)s * f;
  float sn, cs;
  sincosf(ang, &sn, &cs);

  for (int hr = wv; hr < 20; hr += 4) {
    const float* base;
    __hip_bfloat16* dst;
    const float* nw;
    float oscale;
    if (hr < 16) {
      base = row + hr * 128;
      dst = qn + ((size_t)hr * S + s) * 128;
      nw = qw;
      oscale = 0.08838834764831845f;  // 1/sqrt(128) folded into q
    } else {
      const int h4 = hr - 16;
      base = row + 2048 + h4 * 128;
      dst = kn + ((size_t)h4 * S + s) * 128;
      nw = kw;
      oscale = 1.0f;
    }
    const float x1 = base[lane], x2 = base[lane + 64];
    float ss = x1 * x1 + x2 * x2;
#pragma unroll
    for (int mk = 1; mk < 64; mk <<= 1) ss += __shfl_xor(ss, mk);
    const float rms = rsqrtf(ss * (1.0f / 128.0f) + 1e-6f);
    const float x1n = x1 * rms * nw[lane];
    const float x2n = x2 * rms * nw[lane + 64];
    dst[lane]      = __float2bfloat16((x1n * cs - x2n * sn) * oscale);
    dst[lane + 64] = __float2bfloat16((x2n * cs + x1n * sn) * oscale);
  }
  for (int i = tid; i < 512; i += 256) {
    const int h4 = i >> 7, d = i & 127;
    vt[((size_t)h4 * 128 + d) * S + s] = __float2bfloat16(row[2560 + i]);
  }
  for (int i = tid; i < 768; i += 256) {
    if (i < 384) {
      rq[((size_t)(i >> 5) * S + s) * 32 + (i & 31)] = __float2bfloat16(row[3072 + i]);
    } else {
      const int j = i - 384;
      rk[((size_t)(j >> 5) * S + s) * 32 + (j & 31)] = __float2bfloat16(row[3072 + i]);
    }
  }
}

// ---------------- flash attention: barrier-free, LDS-free, swapped QK^T ------
// grid 512, 4 independent waves/block (no __syncthreads anywhere).
// bid&15 = j -> h = (j&3)*4 + (j>>2)  (bid%8 fixes h4 per XCD -> 1MB KV/L2).
// u = bid>>4: qb = u<16 ? 31-u : u-16  (heavy-first, load-balanced pairing).
// Wave owns 16 q-rows. K/V fragments are wave-uniform (swapped operands) and
// read directly from L2-resident kn/vt. Fixed-max softmax, end-of-kernel l.
__global__ __launch_bounds__(256) void attn_kernel(
    const __hip_bfloat16* __restrict__ qn, const __hip_bfloat16* __restrict__ kn,
    const __hip_bfloat16* __restrict__ vt, const __hip_bfloat16* __restrict__ rq,
    const __hip_bfloat16* __restrict__ rk, const float* __restrict__ gsc,
    __hip_bfloat16* __restrict__ ao) {
  constexpr int S = 2048;
  constexpr float L2E = 1.4426950408889634f;
  const int bid = blockIdx.x;
  const int j = bid & 15;
  const int h = ((j & 3) << 2) | (j >> 2);
  const int u = bid >> 4;
  const int qb = (u < 16) ? (31 - u) : (u - 16);
  const int lane = threadIdx.x & 63;
  const int wv = threadIdx.x >> 6;
  const int qs = qb * 64 + wv * 16;
  const int l15 = lane & 15, g = lane >> 4;
  const int h4 = h >> 2;
  const bool has_bias = (h < 12);
  const bool symh = (h < 4);
  const float gs = has_bias ? gsc[h] : 0.0f;
  const f32x4 zf = {0.f, 0.f, 0.f, 0.f};

  // Q as MFMA B-operand fragments: col q = l15, k = kc*32 + g*8 + j
  short8 qf[4];
  {
    const __hip_bfloat16* qrow = qn + ((size_t)h * S + qs + l15) * 128 + g * 8;
#pragma unroll
    for (int kc = 0; kc < 4; ++kc) qf[kc] = *(const short8*)(qrow + kc * 32);
  }
  short8 rqA = {}, rkA = {};
  if (has_bias) rqA = *(const short8*)(rq + ((size_t)h * S + qs + l15) * 32 + g * 8);
  if (symh)     rkA = *(const short8*)(rk + ((size_t)h * S + qs + l15) * 32 + g * 8);

  const __hip_bfloat16* kbase = kn + (size_t)h4 * S * 128;
  const __hip_bfloat16* vbase = vt + (size_t)h4 * 128 * S;
  const __hip_bfloat16* rkp   = rk + (size_t)h * S * 32;
  const __hip_bfloat16* rqp   = rq + (size_t)h * S * 32;

  float lp = 0.0f;  // per-lane partial row-sum for q = qs + l15
  f32x4 acc[8];
#pragma unroll
  for (int fb = 0; fb < 8; ++fb) acc[fb] = zf;

  const int nt = qb + 1;

  // bias A-frags for tile 0 (rows t', k over R=32)
  short8 rkB[4], rqB[4];
  if (has_bias) {
#pragma unroll
    for (int tf = 0; tf < 4; ++tf)
      rkB[tf] = *(const short8*)(rkp + (size_t)(tf * 16 + l15) * 32 + g * 8);
    if (symh) {
#pragma unroll
      for (int tf = 0; tf < 4; ++tf)
        rqB[tf] = *(const short8*)(rqp + (size_t)(tf * 16 + l15) * 32 + g * 8);
    }
  }

  const int srcA = l15 + ((g & 1) << 5);
  const int srcB = srcA + 16;
  const bool ghi = (g >= 2);

  for (int t = 0; t < nt; ++t) {
    const int tbase = t * 64;

    // low-rank bias (swapped): bias^T[t'][q]
    f32x4 bias4[4];
    if (has_bias) {
#pragma unroll
      for (int tf = 0; tf < 4; ++tf) bias4[tf] = mfma16(rkB[tf], rqA, zf);
      if (symh) {
#pragma unroll
        for (int tf = 0; tf < 4; ++tf) {
          f32x4 b2 = mfma16(rqB[tf], rkA, zf);
#pragma unroll
          for (int r = 0; r < 4; ++r) bias4[tf][r] = 0.5f * (bias4[tf][r] + b2[r]);
        }
      }
      if (t + 1 < nt) {  // prefetch next tile's bias A-frags
        const int tb2 = tbase + 64;
#pragma unroll
        for (int tf = 0; tf < 4; ++tf)
          rkB[tf] = *(const short8*)(rkp + (size_t)(tb2 + tf * 16 + l15) * 32 + g * 8);
        if (symh) {
#pragma unroll
          for (int tf = 0; tf < 4; ++tf)
            rqB[tf] = *(const short8*)(rqp + (size_t)(tb2 + tf * 16 + l15) * 32 + g * 8);
        }
      }
    }

    // swapped QK^T, K straight from L2: C[t'][q], t' = tf*16+g*4+r, q = l15
    f32x4 sc[4];
#pragma unroll
    for (int tf = 0; tf < 4; ++tf) {
      f32x4 s4 = zf;
      const __hip_bfloat16* krow = kbase + (size_t)(tbase + tf * 16 + l15) * 128 + g * 8;
#pragma unroll
      for (int kc = 0; kc < 4; ++kc) {
        short8 kf = *(const short8*)(krow + kc * 32);
        s4 = mfma16(kf, qf[kc], s4);
      }
#pragma unroll
      for (int r = 0; r < 4; ++r) {
        float sv = s4[r];
        if (has_bias) sv += gs * bias4[tf][r];
        if (tbase + tf * 16 + g * 4 + r > qs + l15) sv = -1e30f;
        const float p = exp2f(sv * L2E);
        lp += p;
        sc[tf][r] = p;
      }
    }

    // P (C-frag [t'][q]) -> PV A-frag ([q][t]) in-register via shfl
    unsigned int pk0[4], pk1[4];
#pragma unroll
    for (int tf = 0; tf < 4; ++tf) {
      pk0[tf] = bfp(sc[tf][0], sc[tf][1]);
      pk1[tf] = bfp(sc[tf][2], sc[tf][3]);
    }
    unsigned int a0[4], a1[4], b0[4], b1[4];
#pragma unroll
    for (int tf = 0; tf < 4; ++tf) {
      a0[tf] = __shfl(pk0[tf], srcA);
      a1[tf] = __shfl(pk1[tf], srcA);
      b0[tf] = __shfl(pk0[tf], srcB);
      b1[tf] = __shfl(pk1[tf], srcB);
    }
    u32x4 w0 = {ghi ? a0[1] : a0[0], ghi ? a1[1] : a1[0],
                ghi ? b0[1] : b0[0], ghi ? b1[1] : b1[0]};
    u32x4 w1 = {ghi ? a0[3] : a0[2], ghi ? a1[3] : a1[2],
                ghi ? b0[3] : b0[2], ghi ? b1[3] : b1[2]};
    const short8 pa0 = __builtin_bit_cast(short8, w0);
    const short8 pa1 = __builtin_bit_cast(short8, w1);

    // PV, V^T straight from L2: B-frag col d = fb*16+l15, k = t
#pragma unroll
    for (int fb = 0; fb < 8; ++fb) {
      const __hip_bfloat16* vrow = vbase + (size_t)(fb * 16 + l15) * S + tbase + g * 8;
      short8 v0 = *(const short8*)(vrow);
      short8 v1 = *(const short8*)(vrow + 32);
      acc[fb] = mfma16(pa0, v0, acc[fb]);
      acc[fb] = mfma16(pa1, v1, acc[fb]);
    }
  }

  // total l for q = l15 (sum the 4 g-groups), then per-output-row inverse
  float lt = lp;
  lt += __shfl_xor(lt, 16);
  lt += __shfl_xor(lt, 32);
  const float linv = 1.0f / lt;
  float lr[4];
#pragma unroll
  for (int r = 0; r < 4; ++r) lr[r] = __shfl(linv, g * 4 + r);

#pragma unroll
  for (int fb = 0; fb < 8; ++fb)
#pragma unroll
    for (int r = 0; r < 4; ++r) {
      const int srow = qs + g * 4 + r;
      ao[(size_t)srow * 2048 + h * 128 + fb * 16 + l15] =
          __float2bfloat16(acc[fb][r] * lr[r]);
    }
}

// ---------------- launch ----------------
extern "C" void kernel_launch(void* const* d_in, const int* in_sizes, int n_in,
                              void* d_out, int out_size, void* d_ws, size_t ws_size,
                              hipStream_t stream) {
  (void)in_sizes; (void)n_in; (void)out_size; (void)ws_size;
  constexpr int S = 2048, E = 2048;

  const float* x   = (const float*)d_in[0];
  const float* Wq  = (const float*)d_in[1];
  const float* Wk  = (const float*)d_in[2];
  const float* Wv  = (const float*)d_in[3];
  const float* Wo  = (const float*)d_in[4];
  const float* qw  = (const float*)d_in[5];
  const float* kw  = (const float*)d_in[6];
  const float* Wrq = (const float*)d_in[7];
  const float* Wrk = (const float*)d_in[8];
  const float* gsc = (const float*)d_in[9];
  float* out = (float*)d_out;

  char* ws = (char*)d_ws;
  size_t off = 0;
  auto alloc = [&](size_t bytes) -> void* {
    void* p = ws + off;
    off += (bytes + 255) & ~(size_t)255;
    return p;
  };
  __hip_bfloat16* xb   = (__hip_bfloat16*)alloc((size_t)S * E * 2);
  __hip_bfloat16* Wall = (__hip_bfloat16*)alloc((size_t)3840 * E * 2);
  __hip_bfloat16* Wob  = (__hip_bfloat16*)alloc((size_t)E * E * 2);
  __hip_bfloat16* qnb  = (__hip_bfloat16*)alloc((size_t)16 * S * 128 * 2);
  __hip_bfloat16* knb  = (__hip_bfloat16*)alloc((size_t)4 * S * 128 * 2);
  __hip_bfloat16* vtb  = (__hip_bfloat16*)alloc((size_t)4 * 128 * S * 2);
  __hip_bfloat16* rqb  = (__hip_bfloat16*)alloc((size_t)12 * S * 32 * 2);
  __hip_bfloat16* rkb  = (__hip_bfloat16*)alloc((size_t)12 * S * 32 * 2);
  float* C1            = (float*)alloc((size_t)S * 3840 * 4);
  __hip_bfloat16* ao   = (__hip_bfloat16*)C1;  // overlay: C1 dead after postproc

  CastArgs ca;
  ca.seg[0] = {x,   xb,                      (int)((size_t)S * E / 4)};
  ca.seg[1] = {Wq,  Wall,                    (int)((size_t)E * E / 4)};
  ca.seg[2] = {Wk,  Wall + (size_t)2048 * E, (int)((size_t)512 * E / 4)};
  ca.seg[3] = {Wv,  Wall + (size_t)2560 * E, (int)((size_t)512 * E / 4)};
  ca.seg[4] = {Wrq, Wall + (size_t)3072 * E, (int)((size_t)384 * E / 4)};
  ca.seg[5] = {Wrk, Wall + (size_t)3456 * E, (int)((size_t)384 * E / 4)};
  ca.seg[6] = {Wo,  Wob,                     (int)((size_t)E * E / 4)};
  ca.tot4 = 0;
  for (int i = 0; i < 7; ++i) ca.tot4 += ca.seg[i].n4;
  cast_all<<<dim3(2048), dim3(256), 0, stream>>>(ca);

  gemm_bt<<<dim3(30, 32), dim3(256), 0, stream>>>(xb, Wall, C1, 3840, E);
  postproc<<<dim3(2048), dim3(256), 0, stream>>>(C1, qw, kw, qnb, knb, vtb, rqb, rkb);
  attn_kernel<<<dim3(512), dim3(256), 0, stream>>>(qnb, knb, vtb, rqb, rkb, gsc, ao);
  gemm_bt<<<dim3(16, 32), dim3(256), 0, stream>>>(ao, Wob, out, E, E);
}

// Round 7
// 312.423 us; speedup vs baseline: 1.4416x; 1.1498x over previous
//
#include <hip/hip_runtime.h>
#include <hip/hip_bf16.h>

typedef __attribute__((ext_vector_type(8))) short short8;
typedef __attribute__((ext_vector_type(4))) float f32x4;
typedef __attribute__((ext_vector_type(4))) unsigned int u32x4;

__device__ __forceinline__ f32x4 mfma16(short8 a, short8 b, f32x4 c) {
  return __builtin_amdgcn_mfma_f32_16x16x32_bf16(a, b, c, 0, 0, 0);
}

__device__ __forceinline__ void gload_lds16(const void* g, void* l) {
  __builtin_amdgcn_global_load_lds(
      (const __attribute__((address_space(1))) void*)g,
      (__attribute__((address_space(3))) void*)l, 16, 0, 0);
}

__device__ __forceinline__ unsigned int bfp(float lo, float hi) {
  return (unsigned int)__builtin_bit_cast(unsigned short, __float2bfloat16(lo)) |
         ((unsigned int)__builtin_bit_cast(unsigned short, __float2bfloat16(hi)) << 16);
}

// ---------------- merged cast fp32 -> bf16 ----------------
struct __align__(8) bh4 { __hip_bfloat16 a, b, c, d; };
struct CastSeg { const float* src; __hip_bfloat16* dst; int n4; };
struct CastArgs { CastSeg seg[7]; int tot4; };

__global__ __launch_bounds__(256) void cast_all(CastArgs a) {
  int i = blockIdx.x * 256 + threadIdx.x;
  const int stride = gridDim.x * 256;
  for (; i < a.tot4; i += stride) {
    int j = i, s = 0;
    while (j >= a.seg[s].n4) { j -= a.seg[s].n4; ++s; }
    float4 v = ((const float4*)a.seg[s].src)[j];
    bh4 o{__float2bfloat16(v.x), __float2bfloat16(v.y),
          __float2bfloat16(v.z), __float2bfloat16(v.w)};
    ((bh4*)a.seg[s].dst)[j] = o;
  }
}

// ---------------- bf16 GEMM, m97 structure, BM=64 x BN=128: C = A @ B^T ----------
__global__ __launch_bounds__(256) void gemm_bt(const __hip_bfloat16* __restrict__ A,
                                               const __hip_bfloat16* __restrict__ B,
                                               float* __restrict__ C,
                                               int N, int K) {
  __shared__ __align__(16) __hip_bfloat16 As[64][32];
  __shared__ __align__(16) __hip_bfloat16 Bs[128][32];

  const int tid = threadIdx.x;
  const int lane = tid & 63, wv = tid >> 6;
  const int wn = wv * 32;
  const int l15 = lane & 15, g = lane >> 4;
  const int mb = blockIdx.y * 64, nb = blockIdx.x * 128;

  const int arow = wv * 16 + (lane >> 2);
  const int brow = wv * 32 + (lane >> 2);
  const int scol = (lane & 3) * 8;
  const __hip_bfloat16* Ap = A + (size_t)(mb + arow) * K + scol;
  const __hip_bfloat16* Bp = B + (size_t)(nb + brow) * K + scol;
  __hip_bfloat16* lA  = &As[wv * 16][0];
  __hip_bfloat16* lB0 = &Bs[wv * 32][0];
  __hip_bfloat16* lB1 = &Bs[wv * 32 + 16][0];

  const f32x4 zf = {0.f, 0.f, 0.f, 0.f};
  f32x4 acc[4][2];
#pragma unroll
  for (int m = 0; m < 4; ++m)
#pragma unroll
    for (int n = 0; n < 2; ++n) acc[m][n] = zf;

  for (int k0 = 0; k0 < K; k0 += 32) {
    __syncthreads();
    gload_lds16(Ap + k0, lA);
    gload_lds16(Bp + k0, lB0);
    gload_lds16(Bp + (size_t)16 * K + k0, lB1);
    __syncthreads();
    short8 af[4], bf[2];
#pragma unroll
    for (int m = 0; m < 4; ++m) af[m] = *(const short8*)&As[m * 16 + l15][g * 8];
#pragma unroll
    for (int n = 0; n < 2; ++n) bf[n] = *(const short8*)&Bs[wn + n * 16 + l15][g * 8];
#pragma unroll
    for (int m = 0; m < 4; ++m)
#pragma unroll
      for (int n = 0; n < 2; ++n) acc[m][n] = mfma16(af[m], bf[n], acc[m][n]);
  }

#pragma unroll
  for (int m = 0; m < 4; ++m)
#pragma unroll
    for (int n = 0; n < 2; ++n)
#pragma unroll
      for (int r = 0; r < 4; ++r)
        C[(size_t)(mb + m * 16 + g * 4 + r) * N + (nb + wn + n * 16 + l15)] =
            acc[m][n][r];
}

// ---------------- post-process: RMSNorm + RoPE + layout changes ----------------
__global__ __launch_bounds__(256) void postproc(const float* __restrict__ C1,
                                                const float* __restrict__ qw,
                                                const float* __restrict__ kw,
                                                __hip_bfloat16* __restrict__ qn,
                                                __hip_bfloat16* __restrict__ kn,
                                                __hip_bfloat16* __restrict__ vt,
                                                __hip_bfloat16* __restrict__ rq,
                                                __hip_bfloat16* __restrict__ rk) {
  constexpr int S = 2048;
  const int s = blockIdx.x;
  const int tid = threadIdx.x;
  const int lane = tid & 63;
  const int wv = tid >> 6;
  const float* row = C1 + (size_t)s * 3840;

  const float f = exp2f(-(float)lane * (13.287712379549449f / 64.0f));
  const float ang = (float)s * f;
  float sn, cs;
  sincosf(ang, &sn, &cs);

  for (int hr = wv; hr < 20; hr += 4) {
    const float* base;
    __hip_bfloat16* dst;
    const float* nw;
    float oscale;
    if (hr < 16) {
      base = row + hr * 128;
      dst = qn + ((size_t)hr * S + s) * 128;
      nw = qw;
      oscale = 0.08838834764831845f;  // 1/sqrt(128) folded into q
    } else {
      const int h4 = hr - 16;
      base = row + 2048 + h4 * 128;
      dst = kn + ((size_t)h4 * S + s) * 128;
      nw = kw;
      oscale = 1.0f;
    }
    const float x1 = base[lane], x2 = base[lane + 64];
    float ss = x1 * x1 + x2 * x2;
#pragma unroll
    for (int mk = 1; mk < 64; mk <<= 1) ss += __shfl_xor(ss, mk);
    const float rms = rsqrtf(ss * (1.0f / 128.0f) + 1e-6f);
    const float x1n = x1 * rms * nw[lane];
    const float x2n = x2 * rms * nw[lane + 64];
    dst[lane]      = __float2bfloat16((x1n * cs - x2n * sn) * oscale);
    dst[lane + 64] = __float2bfloat16((x2n * cs + x1n * sn) * oscale);
  }
  for (int i = tid; i < 512; i += 256) {
    const int h4 = i >> 7, d = i & 127;
    vt[((size_t)h4 * 128 + d) * S + s] = __float2bfloat16(row[2560 + i]);
  }
  for (int i = tid; i < 768; i += 256) {
    if (i < 384) {
      rq[((size_t)(i >> 5) * S + s) * 32 + (i & 31)] = __float2bfloat16(row[3072 + i]);
    } else {
      const int j = i - 384;
      rk[((size_t)(j >> 5) * S + s) * 32 + (j & 31)] = __float2bfloat16(row[3072 + i]);
    }
  }
}

// ---------------- flash attention: LDS-staged KV + in-register P transform ----
// grid 512: j=bid&15 -> h=((j&3)<<2)|(j>>2) pins h4 = bid&3 per XCD (KV slice
// 1MB L2-resident). u=bid>>4: qb = u<16 ? 31-u : u-16 (heavy+light pairing).
// 4 waves x 16 q-rows. KV tile 64, double-buffered swizzled LDS, ONE barrier
// per tile, loads issued 2 tiles ahead. Swapped QK^T, fixed-max softmax,
// P C-frag -> PV A-frag via in-register shfl (no p_lds roundtrip).
__global__ __launch_bounds__(256) void attn_kernel(
    const __hip_bfloat16* __restrict__ qn, const __hip_bfloat16* __restrict__ kn,
    const __hip_bfloat16* __restrict__ vt, const __hip_bfloat16* __restrict__ rq,
    const __hip_bfloat16* __restrict__ rk, const float* __restrict__ gsc,
    __hip_bfloat16* __restrict__ ao) {
  constexpr int S = 2048;
  constexpr float L2E = 1.4426950408889634f;
  const int bid = blockIdx.x;
  const int j = bid & 15;
  const int h = ((j & 3) << 2) | (j >> 2);
  const int u = bid >> 4;
  const int qb = (u < 16) ? (31 - u) : (u - 16);
  const int tid = threadIdx.x;
  const int lane = tid & 63;
  const int wv = tid >> 6;
  const int qs = qb * 64 + wv * 16;
  const int l15 = lane & 15, g = lane >> 4;
  const int h4 = h >> 2;
  const bool has_bias = (h < 12);
  const bool symh = (h < 4);
  const float gs = has_bias ? gsc[h] : 0.0f;
  const f32x4 zf = {0.f, 0.f, 0.f, 0.f};

  // K [64][128] bf16 (16KB) + V [128][64] (16KB), x2 buffers, XOR-swizzled:
  // physical byte = linear byte ^ ((row&7)<<4).
  __shared__ __align__(16) char KsRaw[2][16384];
  __shared__ __align__(16) char VsRaw[2][16384];

  const int sxk = ((tid >> 4) & 7) << 4;
  const int sxv = ((tid >> 3) & 7) << 4;
  const int k_wr = (tid * 16) ^ sxk;
  const int v_wr = (tid * 16) ^ sxv;
  const int kx = (l15 & 7) << 4;

  const __hip_bfloat16* kbase = kn + (size_t)h4 * S * 128;
  const __hip_bfloat16* vbase = vt + (size_t)h4 * 128 * S;
  const __hip_bfloat16* rkp   = rk + (size_t)h * S * 32;
  const __hip_bfloat16* rqp   = rq + (size_t)h * S * 32;

  // Q as MFMA B-operand fragments: col q = l15, k = kc*32 + g*8 + e
  short8 qf[4];
  {
    const __hip_bfloat16* qrow = qn + ((size_t)h * S + qs + l15) * 128 + g * 8;
#pragma unroll
    for (int kc = 0; kc < 4; ++kc) qf[kc] = *(const short8*)(qrow + kc * 32);
  }
  short8 rqA = {}, rkA = {};
  if (has_bias) rqA = *(const short8*)(rqp + (size_t)(qs + l15) * 32 + g * 8);
  if (symh)     rkA = *(const short8*)(rkp + (size_t)(qs + l15) * 32 + g * 8);

  float lp = 0.0f;  // per-lane partial row-sum for q = qs + l15
  f32x4 acc[8];
#pragma unroll
  for (int fb = 0; fb < 8; ++fb) acc[fb] = zf;

  const int nt = qb + 1;

  // staging loads (per thread: 4x16B K chunks, 4x16B V chunks)
  short8 kreg[4], vreg[4];
  auto load_kv = [&](int tb) {
#pragma unroll
    for (int c = 0; c < 4; ++c) {
      kreg[c] = *(const short8*)(kbase + ((size_t)(tb + c * 16 + (tid >> 4))) * 128 + (tid & 15) * 8);
      vreg[c] = *(const short8*)(vbase + ((size_t)(c * 32 + (tid >> 3))) * S + tb + (tid & 7) * 8);
    }
  };

  // prologue: stage tile 0 into buf0, issue loads for tile 1
  load_kv(0);
#pragma unroll
  for (int c = 0; c < 4; ++c) {
    *(short8*)(&KsRaw[0][c * 4096 + k_wr]) = kreg[c];
    *(short8*)(&VsRaw[0][c * 4096 + v_wr]) = vreg[c];
  }
  if (nt > 1) load_kv(64);

  // bias A-frags for tile 0 (rows t', k over R=32)
  short8 rkB[4], rqB[4];
  if (has_bias) {
#pragma unroll
    for (int tf = 0; tf < 4; ++tf)
      rkB[tf] = *(const short8*)(rkp + (size_t)(tf * 16 + l15) * 32 + g * 8);
    if (symh) {
#pragma unroll
      for (int tf = 0; tf < 4; ++tf)
        rqB[tf] = *(const short8*)(rqp + (size_t)(tf * 16 + l15) * 32 + g * 8);
    }
  }

  const int srcA = l15 + ((g & 1) << 5);
  const int srcB = srcA + 16;
  const bool ghi = (g >= 2);

  __syncthreads();  // buf0 staged

  for (int t = 0; t < nt; ++t) {
    const int tbase = t * 64;
    const int cur = t & 1;
    const char* ksb = &KsRaw[cur][0];
    const char* vsb = &VsRaw[cur][0];

    // buf^1 is free (its tile t-1 readers finished before the last barrier):
    // commit tile t+1 (regs -> LDS), then issue tile t+2 global loads.
    if (t + 1 < nt) {
      char* ksw = &KsRaw[cur ^ 1][0];
      char* vsw = &VsRaw[cur ^ 1][0];
#pragma unroll
      for (int c = 0; c < 4; ++c) {
        *(short8*)(ksw + c * 4096 + k_wr) = kreg[c];
        *(short8*)(vsw + c * 4096 + v_wr) = vreg[c];
      }
      if (t + 2 < nt) load_kv(tbase + 128);
    }

    // low-rank bias (swapped): bias^T[t'][q], then prefetch next tile's frags
    f32x4 bias4[4];
    if (has_bias) {
#pragma unroll
      for (int tf = 0; tf < 4; ++tf) bias4[tf] = mfma16(rkB[tf], rqA, zf);
      if (symh) {
#pragma unroll
        for (int tf = 0; tf < 4; ++tf) {
          f32x4 b2 = mfma16(rqB[tf], rkA, zf);
#pragma unroll
          for (int r = 0; r < 4; ++r) bias4[tf][r] = 0.5f * (bias4[tf][r] + b2[r]);
        }
      }
      if (t + 1 < nt) {
        const int tb2 = tbase + 64;
#pragma unroll
        for (int tf = 0; tf < 4; ++tf)
          rkB[tf] = *(const short8*)(rkp + (size_t)(tb2 + tf * 16 + l15) * 32 + g * 8);
        if (symh) {
#pragma unroll
          for (int tf = 0; tf < 4; ++tf)
            rqB[tf] = *(const short8*)(rqp + (size_t)(tb2 + tf * 16 + l15) * 32 + g * 8);
        }
      }
    }

    // swapped QK^T from swizzled LDS: C[t'][q], t' = tf*16+g*4+r, q = l15
    f32x4 sc[4];
#pragma unroll
    for (int tf = 0; tf < 4; ++tf) {
      f32x4 s4 = zf;
#pragma unroll
      for (int kc = 0; kc < 4; ++kc) {
        short8 kf = *(const short8*)(ksb + ((((tf * 16 + l15) << 8) + (kc << 6) + (g << 4)) ^ kx));
        s4 = mfma16(kf, qf[kc], s4);
      }
#pragma unroll
      for (int r = 0; r < 4; ++r) {
        float sv = s4[r];
        if (has_bias) sv += gs * bias4[tf][r];
        if (tbase + tf * 16 + g * 4 + r > qs + l15) sv = -1e30f;
        const float p = exp2f(sv * L2E);
        lp += p;
        sc[tf][r] = p;
      }
    }

    // P (C-frag [t'][q]) -> PV A-frag ([q][t]) in-register via shfl
    unsigned int pk0[4], pk1[4];
#pragma unroll
    for (int tf = 0; tf < 4; ++tf) {
      pk0[tf] = bfp(sc[tf][0], sc[tf][1]);
      pk1[tf] = bfp(sc[tf][2], sc[tf][3]);
    }
    unsigned int a0[4], a1[4], b0[4], b1[4];
#pragma unroll
    for (int tf = 0; tf < 4; ++tf) {
      a0[tf] = __shfl(pk0[tf], srcA);
      a1[tf] = __shfl(pk1[tf], srcA);
      b0[tf] = __shfl(pk0[tf], srcB);
      b1[tf] = __shfl(pk1[tf], srcB);
    }
    u32x4 w0 = {ghi ? a0[1] : a0[0], ghi ? a1[1] : a1[0],
                ghi ? b0[1] : b0[0], ghi ? b1[1] : b1[0]};
    u32x4 w1 = {ghi ? a0[3] : a0[2], ghi ? a1[3] : a1[2],
                ghi ? b0[3] : b0[2], ghi ? b1[3] : b1[2]};
    const short8 pa0 = __builtin_bit_cast(short8, w0);
    const short8 pa1 = __builtin_bit_cast(short8, w1);

    // PV from swizzled LDS: B-frag col d = fb*16+l15, k = t
#pragma unroll
    for (int fb = 0; fb < 8; ++fb) {
      short8 v0 = *(const short8*)(vsb + ((((fb * 16 + l15) << 7) + (g << 4)) ^ kx));
      short8 v1 = *(const short8*)(vsb + ((((fb * 16 + l15) << 7) + 64 + (g << 4)) ^ kx));
      acc[fb] = mfma16(pa0, v0, acc[fb]);
      acc[fb] = mfma16(pa1, v1, acc[fb]);
    }

    __syncthreads();  // readers of buf[cur] done; buf[cur^1] writes published
  }

  // total l for q = l15 (sum the 4 g-groups), then per-output-row inverse
  float lt = lp;
  lt += __shfl_xor(lt, 16);
  lt += __shfl_xor(lt, 32);
  const float linv = 1.0f / lt;
  float lr[4];
#pragma unroll
  for (int r = 0; r < 4; ++r) lr[r] = __shfl(linv, g * 4 + r);

#pragma unroll
  for (int fb = 0; fb < 8; ++fb)
#pragma unroll
    for (int r = 0; r < 4; ++r) {
      const int srow = qs + g * 4 + r;
      ao[(size_t)srow * 2048 + h * 128 + fb * 16 + l15] =
          __float2bfloat16(acc[fb][r] * lr[r]);
    }
}

// ---------------- launch ----------------
extern "C" void kernel_launch(void* const* d_in, const int* in_sizes, int n_in,
                              void* d_out, int out_size, void* d_ws, size_t ws_size,
                              hipStream_t stream) {
  (void)in_sizes; (void)n_in; (void)out_size; (void)ws_size;
  constexpr int S = 2048, E = 2048;

  const float* x   = (const float*)d_in[0];
  const float* Wq  = (const float*)d_in[1];
  const float* Wk  = (const float*)d_in[2];
  const float* Wv  = (const float*)d_in[3];
  const float* Wo  = (const float*)d_in[4];
  const float* qw  = (const float*)d_in[5];
  const float* kw  = (const float*)d_in[6];
  const float* Wrq = (const float*)d_in[7];
  const float* Wrk = (const float*)d_in[8];
  const float* gsc = (const float*)d_in[9];
  float* out = (float*)d_out;

  char* ws = (char*)d_ws;
  size_t off = 0;
  auto alloc = [&](size_t bytes) -> void* {
    void* p = ws + off;
    off += (bytes + 255) & ~(size_t)255;
    return p;
  };
  __hip_bfloat16* xb   = (__hip_bfloat16*)alloc((size_t)S * E * 2);
  __hip_bfloat16* Wall = (__hip_bfloat16*)alloc((size_t)3840 * E * 2);
  __hip_bfloat16* Wob  = (__hip_bfloat16*)alloc((size_t)E * E * 2);
  __hip_bfloat16* qnb  = (__hip_bfloat16*)alloc((size_t)16 * S * 128 * 2);
  __hip_bfloat16* knb  = (__hip_bfloat16*)alloc((size_t)4 * S * 128 * 2);
  __hip_bfloat16* vtb  = (__hip_bfloat16*)alloc((size_t)4 * 128 * S * 2);
  __hip_bfloat16* rqb  = (__hip_bfloat16*)alloc((size_t)12 * S * 32 * 2);
  __hip_bfloat16* rkb  = (__hip_bfloat16*)alloc((size_t)12 * S * 32 * 2);
  float* C1            = (float*)alloc((size_t)S * 3840 * 4);
  __hip_bfloat16* ao   = (__hip_bfloat16*)C1;  // overlay: C1 dead after postproc

  CastArgs ca;
  ca.seg[0] = {x,   xb,                      (int)((size_t)S * E / 4)};
  ca.seg[1] = {Wq,  Wall,                    (int)((size_t)E * E / 4)};
  ca.seg[2] = {Wk,  Wall + (size_t)2048 * E, (int)((size_t)512 * E / 4)};
  ca.seg[3] = {Wv,  Wall + (size_t)2560 * E, (int)((size_t)512 * E / 4)};
  ca.seg[4] = {Wrq, Wall + (size_t)3072 * E, (int)((size_t)384 * E / 4)};
  ca.seg[5] = {Wrk, Wall + (size_t)3456 * E, (int)((size_t)384 * E / 4)};
  ca.seg[6] = {Wo,  Wob,                     (int)((size_t)E * E / 4)};
  ca.tot4 = 0;
  for (int i = 0; i < 7; ++i) ca.tot4 += ca.seg[i].n4;
  cast_all<<<dim3(2048), dim3(256), 0, stream>>>(ca);

  gemm_bt<<<dim3(30, 32), dim3(256), 0, stream>>>(xb, Wall, C1, 3840, E);
  postproc<<<dim3(2048), dim3(256), 0, stream>>>(C1, qw, kw, qnb, knb, vtb, rqb, rkb);
  attn_kernel<<<dim3(512), dim3(256), 0, stream>>>(qnb, knb, vtb, rqb, rkb, gsc, ao);
  gemm_bt<<<dim3(16, 32), dim3(256), 0, stream>>>(ao, Wob, out, E, E);
}

// Round 8
// 293.064 us; speedup vs baseline: 1.5368x; 1.0661x over previous
//
#include <hip/hip_runtime.h>
#include <hip/hip_bf16.h>

typedef __attribute__((ext_vector_type(8))) short short8;
typedef __attribute__((ext_vector_type(4))) float f32x4;
typedef __attribute__((ext_vector_type(4))) unsigned int u32x4;

__device__ __forceinline__ f32x4 mfma16(short8 a, short8 b, f32x4 c) {
  return __builtin_amdgcn_mfma_f32_16x16x32_bf16(a, b, c, 0, 0, 0);
}

__device__ __forceinline__ void gload_lds16(const void* g, void* l) {
  __builtin_amdgcn_global_load_lds(
      (const __attribute__((address_space(1))) void*)g,
      (__attribute__((address_space(3))) void*)l, 16, 0, 0);
}

__device__ __forceinline__ unsigned int bfp(float lo, float hi) {
  return (unsigned int)__builtin_bit_cast(unsigned short, __float2bfloat16(lo)) |
         ((unsigned int)__builtin_bit_cast(unsigned short, __float2bfloat16(hi)) << 16);
}

// ---------------- merged cast fp32 -> bf16 ----------------
struct __align__(8) bh4 { __hip_bfloat16 a, b, c, d; };
struct CastSeg { const float* src; __hip_bfloat16* dst; int n4; };
struct CastArgs { CastSeg seg[7]; int tot4; };

__global__ __launch_bounds__(256) void cast_all(CastArgs a) {
  int i = blockIdx.x * 256 + threadIdx.x;
  const int stride = gridDim.x * 256;
  for (; i < a.tot4; i += stride) {
    int j = i, s = 0;
    while (j >= a.seg[s].n4) { j -= a.seg[s].n4; ++s; }
    float4 v = ((const float4*)a.seg[s].src)[j];
    bh4 o{__float2bfloat16(v.x), __float2bfloat16(v.y),
          __float2bfloat16(v.z), __float2bfloat16(v.w)};
    ((bh4*)a.seg[s].dst)[j] = o;
  }
}

// ---------------- bf16 GEMM, m97 structure, BM=64 x BN=128: C = A @ B^T ----------
__global__ __launch_bounds__(256) void gemm_bt(const __hip_bfloat16* __restrict__ A,
                                               const __hip_bfloat16* __restrict__ B,
                                               float* __restrict__ C,
                                               int N, int K) {
  __shared__ __align__(16) __hip_bfloat16 As[64][32];
  __shared__ __align__(16) __hip_bfloat16 Bs[128][32];

  const int tid = threadIdx.x;
  const int lane = tid & 63, wv = tid >> 6;
  const int wn = wv * 32;
  const int l15 = lane & 15, g = lane >> 4;
  const int mb = blockIdx.y * 64, nb = blockIdx.x * 128;

  const int arow = wv * 16 + (lane >> 2);
  const int brow = wv * 32 + (lane >> 2);
  const int scol = (lane & 3) * 8;
  const __hip_bfloat16* Ap = A + (size_t)(mb + arow) * K + scol;
  const __hip_bfloat16* Bp = B + (size_t)(nb + brow) * K + scol;
  __hip_bfloat16* lA  = &As[wv * 16][0];
  __hip_bfloat16* lB0 = &Bs[wv * 32][0];
  __hip_bfloat16* lB1 = &Bs[wv * 32 + 16][0];

  const f32x4 zf = {0.f, 0.f, 0.f, 0.f};
  f32x4 acc[4][2];
#pragma unroll
  for (int m = 0; m < 4; ++m)
#pragma unroll
    for (int n = 0; n < 2; ++n) acc[m][n] = zf;

  for (int k0 = 0; k0 < K; k0 += 32) {
    __syncthreads();
    gload_lds16(Ap + k0, lA);
    gload_lds16(Bp + k0, lB0);
    gload_lds16(Bp + (size_t)16 * K + k0, lB1);
    __syncthreads();
    short8 af[4], bf[2];
#pragma unroll
    for (int m = 0; m < 4; ++m) af[m] = *(const short8*)&As[m * 16 + l15][g * 8];
#pragma unroll
    for (int n = 0; n < 2; ++n) bf[n] = *(const short8*)&Bs[wn + n * 16 + l15][g * 8];
#pragma unroll
    for (int m = 0; m < 4; ++m)
#pragma unroll
      for (int n = 0; n < 2; ++n) acc[m][n] = mfma16(af[m], bf[n], acc[m][n]);
  }

#pragma unroll
  for (int m = 0; m < 4; ++m)
#pragma unroll
    for (int n = 0; n < 2; ++n)
#pragma unroll
      for (int r = 0; r < 4; ++r)
        C[(size_t)(mb + m * 16 + g * 4 + r) * N + (nb + wn + n * 16 + l15)] =
            acc[m][n][r];
}

// ---------------- post-process: RMSNorm + RoPE + Rq/Rk pack (V handled separately)
__global__ __launch_bounds__(256) void postproc(const float* __restrict__ C1,
                                                const float* __restrict__ qw,
                                                const float* __restrict__ kw,
                                                __hip_bfloat16* __restrict__ qn,
                                                __hip_bfloat16* __restrict__ kn,
                                                __hip_bfloat16* __restrict__ rq,
                                                __hip_bfloat16* __restrict__ rk) {
  constexpr int S = 2048;
  const int s = blockIdx.x;
  const int tid = threadIdx.x;
  const int lane = tid & 63;
  const int wv = tid >> 6;
  const float* row = C1 + (size_t)s * 3840;

  const float f = exp2f(-(float)lane * (13.287712379549449f / 64.0f));
  const float ang = (float)s * f;
  float sn, cs;
  sincosf(ang, &sn, &cs);

  for (int hr = wv; hr < 20; hr += 4) {
    const float* base;
    __hip_bfloat16* dst;
    const float* nw;
    float oscale;
    if (hr < 16) {
      base = row + hr * 128;
      dst = qn + ((size_t)hr * S + s) * 128;
      nw = qw;
      oscale = 0.08838834764831845f;  // 1/sqrt(128) folded into q
    } else {
      const int h4 = hr - 16;
      base = row + 2048 + h4 * 128;
      dst = kn + ((size_t)h4 * S + s) * 128;
      nw = kw;
      oscale = 1.0f;
    }
    const float x1 = base[lane], x2 = base[lane + 64];
    float ss = x1 * x1 + x2 * x2;
#pragma unroll
    for (int mk = 1; mk < 64; mk <<= 1) ss += __shfl_xor(ss, mk);
    const float rms = rsqrtf(ss * (1.0f / 128.0f) + 1e-6f);
    const float x1n = x1 * rms * nw[lane];
    const float x2n = x2 * rms * nw[lane + 64];
    dst[lane]      = __float2bfloat16((x1n * cs - x2n * sn) * oscale);
    dst[lane + 64] = __float2bfloat16((x2n * cs + x1n * sn) * oscale);
  }
  for (int i = tid; i < 768; i += 256) {
    if (i < 384) {
      rq[((size_t)(i >> 5) * S + s) * 32 + (i & 31)] = __float2bfloat16(row[3072 + i]);
    } else {
      const int j = i - 384;
      rk[((size_t)(j >> 5) * S + s) * 32 + (j & 31)] = __float2bfloat16(row[3072 + i]);
    }
  }
}

// ---------------- V transpose via LDS (coalesced both sides) ----------------
// grid 256: h4 = b>>6, s0 = (b&63)*32. Reads C1 v-slice 32x128 f32 (coalesced),
// writes vt[(h4*128+d)*2048 + s0..s0+31] as 64B-contiguous chunks.
__global__ __launch_bounds__(256) void transpose_v(const float* __restrict__ C1,
                                                   __hip_bfloat16* __restrict__ vt) {
  __shared__ float T[32][129];
  const int b = blockIdx.x;
  const int h4 = b >> 6;
  const int s0 = (b & 63) * 32;
  const int tid = threadIdx.x;
  for (int idx = tid; idx < 4096; idx += 256) {
    const int s = idx >> 7, d = idx & 127;
    T[s][d] = C1[(size_t)(s0 + s) * 3840 + 2560 + h4 * 128 + d];
  }
  __syncthreads();
  for (int j = tid; j < 4096; j += 256) {
    const int d = j >> 5, s = j & 31;
    vt[(size_t)(h4 * 128 + d) * 2048 + s0 + s] = __float2bfloat16(T[s][d]);
  }
}

// ---------------- flash attention: LDS-staged KV + in-register P transform ----
// grid 512: j=bid&15 -> h=((j&3)<<2)|(j>>2) pins h4 = bid&3 per XCD pair.
// u=bid>>4: qb = u<16 ? 31-u : u-16 (heavy-first pairing). 4 waves x 16 rows.
// KV tile 64, dbuf swizzled LDS, ONE barrier/tile, write-late ordering
// (compute -> stage t+1 -> issue t+2 loads -> barrier). Swapped QK^T,
// fixed-max softmax, P C-frag -> PV A-frag via in-register shfl.
__global__ __launch_bounds__(256) void attn_kernel(
    const __hip_bfloat16* __restrict__ qn, const __hip_bfloat16* __restrict__ kn,
    const __hip_bfloat16* __restrict__ vt, const __hip_bfloat16* __restrict__ rq,
    const __hip_bfloat16* __restrict__ rk, const float* __restrict__ gsc,
    __hip_bfloat16* __restrict__ ao) {
  constexpr int S = 2048;
  constexpr float L2E = 1.4426950408889634f;
  const int bid = blockIdx.x;
  const int j = bid & 15;
  const int h = ((j & 3) << 2) | (j >> 2);
  const int u = bid >> 4;
  const int qb = (u < 16) ? (31 - u) : (u - 16);
  const int tid = threadIdx.x;
  const int lane = tid & 63;
  const int wv = tid >> 6;
  const int qs = qb * 64 + wv * 16;
  const int l15 = lane & 15, g = lane >> 4;
  const int h4 = h >> 2;
  const bool has_bias = (h < 12);
  const bool symh = (h < 4);
  const float gs = has_bias ? gsc[h] : 0.0f;
  const f32x4 zf = {0.f, 0.f, 0.f, 0.f};

  __shared__ __align__(16) char KsRaw[2][16384];
  __shared__ __align__(16) char VsRaw[2][16384];

  const int sxk = ((tid >> 4) & 7) << 4;
  const int sxv = ((tid >> 3) & 7) << 4;
  const int k_wr = (tid * 16) ^ sxk;
  const int v_wr = (tid * 16) ^ sxv;
  const int kx = (l15 & 7) << 4;

  const __hip_bfloat16* kbase = kn + (size_t)h4 * S * 128;
  const __hip_bfloat16* vbase = vt + (size_t)h4 * 128 * S;
  const __hip_bfloat16* rkp   = rk + (size_t)h * S * 32;
  const __hip_bfloat16* rqp   = rq + (size_t)h * S * 32;

  // Q as MFMA B-operand fragments: col q = l15, k = kc*32 + g*8 + e
  short8 qf[4];
  {
    const __hip_bfloat16* qrow = qn + ((size_t)h * S + qs + l15) * 128 + g * 8;
#pragma unroll
    for (int kc = 0; kc < 4; ++kc) qf[kc] = *(const short8*)(qrow + kc * 32);
  }
  short8 rqA = {}, rkA = {};
  if (has_bias) rqA = *(const short8*)(rqp + (size_t)(qs + l15) * 32 + g * 8);
  if (symh)     rkA = *(const short8*)(rkp + (size_t)(qs + l15) * 32 + g * 8);

  float lp = 0.0f;  // per-lane partial row-sum for q = qs + l15
  f32x4 acc[8];
#pragma unroll
  for (int fb = 0; fb < 8; ++fb) acc[fb] = zf;

  const int nt = qb + 1;

  short8 kreg[4], vreg[4];
  auto load_kv = [&](int tb) {
#pragma unroll
    for (int c = 0; c < 4; ++c) {
      kreg[c] = *(const short8*)(kbase + ((size_t)(tb + c * 16 + (tid >> 4))) * 128 + (tid & 15) * 8);
      vreg[c] = *(const short8*)(vbase + ((size_t)(c * 32 + (tid >> 3))) * S + tb + (tid & 7) * 8);
    }
  };

  // prologue: stage tile 0 into buf0, issue loads for tile 1
  load_kv(0);
#pragma unroll
  for (int c = 0; c < 4; ++c) {
    *(short8*)(&KsRaw[0][c * 4096 + k_wr]) = kreg[c];
    *(short8*)(&VsRaw[0][c * 4096 + v_wr]) = vreg[c];
  }
  if (nt > 1) load_kv(64);

  short8 rkB[4], rqB[4];
  if (has_bias) {
#pragma unroll
    for (int tf = 0; tf < 4; ++tf)
      rkB[tf] = *(const short8*)(rkp + (size_t)(tf * 16 + l15) * 32 + g * 8);
    if (symh) {
#pragma unroll
      for (int tf = 0; tf < 4; ++tf)
        rqB[tf] = *(const short8*)(rqp + (size_t)(tf * 16 + l15) * 32 + g * 8);
    }
  }

  const int srcA = l15 + ((g & 1) << 5);
  const int srcB = srcA + 16;
  const bool ghi = (g >= 2);

  __syncthreads();  // buf0 staged

  for (int t = 0; t < nt; ++t) {
    const int tbase = t * 64;
    const int cur = t & 1;
    const char* ksb = &KsRaw[cur][0];
    const char* vsb = &VsRaw[cur][0];

    // low-rank bias (swapped): bias^T[t'][q], then prefetch next tile's frags
    f32x4 bias4[4];
    if (has_bias) {
#pragma unroll
      for (int tf = 0; tf < 4; ++tf) bias4[tf] = mfma16(rkB[tf], rqA, zf);
      if (symh) {
#pragma unroll
        for (int tf = 0; tf < 4; ++tf) {
          f32x4 b2 = mfma16(rqB[tf], rkA, zf);
#pragma unroll
          for (int r = 0; r < 4; ++r) bias4[tf][r] = 0.5f * (bias4[tf][r] + b2[r]);
        }
      }
      if (t + 1 < nt) {
        const int tb2 = tbase + 64;
#pragma unroll
        for (int tf = 0; tf < 4; ++tf)
          rkB[tf] = *(const short8*)(rkp + (size_t)(tb2 + tf * 16 + l15) * 32 + g * 8);
        if (symh) {
#pragma unroll
          for (int tf = 0; tf < 4; ++tf)
            rqB[tf] = *(const short8*)(rqp + (size_t)(tb2 + tf * 16 + l15) * 32 + g * 8);
        }
      }
    }

    // swapped QK^T from swizzled LDS: C[t'][q], t' = tf*16+g*4+r, q = l15
    f32x4 sc[4];
#pragma unroll
    for (int tf = 0; tf < 4; ++tf) {
      f32x4 s4 = zf;
#pragma unroll
      for (int kc = 0; kc < 4; ++kc) {
        short8 kf = *(const short8*)(ksb + ((((tf * 16 + l15) << 8) + (kc << 6) + (g << 4)) ^ kx));
        s4 = mfma16(kf, qf[kc], s4);
      }
#pragma unroll
      for (int r = 0; r < 4; ++r) {
        float sv = s4[r];
        if (has_bias) sv += gs * bias4[tf][r];
        if (tbase + tf * 16 + g * 4 + r > qs + l15) sv = -1e30f;
        const float p = exp2f(sv * L2E);
        lp += p;
        sc[tf][r] = p;
      }
    }

    // P (C-frag [t'][q]) -> PV A-frag ([q][t]) in-register via shfl
    unsigned int pk0[4], pk1[4];
#pragma unroll
    for (int tf = 0; tf < 4; ++tf) {
      pk0[tf] = bfp(sc[tf][0], sc[tf][1]);
      pk1[tf] = bfp(sc[tf][2], sc[tf][3]);
    }
    unsigned int a0[4], a1[4], b0[4], b1[4];
#pragma unroll
    for (int tf = 0; tf < 4; ++tf) {
      a0[tf] = __shfl(pk0[tf], srcA);
      a1[tf] = __shfl(pk1[tf], srcA);
      b0[tf] = __shfl(pk0[tf], srcB);
      b1[tf] = __shfl(pk1[tf], srcB);
    }
    u32x4 w0 = {ghi ? a0[1] : a0[0], ghi ? a1[1] : a1[0],
                ghi ? b0[1] : b0[0], ghi ? b1[1] : b1[0]};
    u32x4 w1 = {ghi ? a0[3] : a0[2], ghi ? a1[3] : a1[2],
                ghi ? b0[3] : b0[2], ghi ? b1[3] : b1[2]};
    const short8 pa0 = __builtin_bit_cast(short8, w0);
    const short8 pa1 = __builtin_bit_cast(short8, w1);

    // PV from swizzled LDS: B-frag col d = fb*16+l15, k = t
#pragma unroll
    for (int fb = 0; fb < 8; ++fb) {
      short8 v0 = *(const short8*)(vsb + ((((fb * 16 + l15) << 7) + (g << 4)) ^ kx));
      short8 v1 = *(const short8*)(vsb + ((((fb * 16 + l15) << 7) + 64 + (g << 4)) ^ kx));
      acc[fb] = mfma16(pa0, v0, acc[fb]);
      acc[fb] = mfma16(pa1, v1, acc[fb]);
    }

    // write-late: commit tile t+1 (regs -> buf^1), then issue t+2 loads
    if (t + 1 < nt) {
      char* ksw = &KsRaw[cur ^ 1][0];
      char* vsw = &VsRaw[cur ^ 1][0];
#pragma unroll
      for (int c = 0; c < 4; ++c) {
        *(short8*)(ksw + c * 4096 + k_wr) = kreg[c];
        *(short8*)(vsw + c * 4096 + v_wr) = vreg[c];
      }
      if (t + 2 < nt) load_kv(tbase + 128);
    }
    __syncthreads();  // buf[cur] readers done; buf[cur^1] writes published
  }

  // total l for q = l15 (sum the 4 g-groups), then per-output-row inverse
  float lt = lp;
  lt += __shfl_xor(lt, 16);
  lt += __shfl_xor(lt, 32);
  const float linv = 1.0f / lt;
  float lr[4];
#pragma unroll
  for (int r = 0; r < 4; ++r) lr[r] = __shfl(linv, g * 4 + r);

#pragma unroll
  for (int fb = 0; fb < 8; ++fb)
#pragma unroll
    for (int r = 0; r < 4; ++r) {
      const int srow = qs + g * 4 + r;
      ao[(size_t)srow * 2048 + h * 128 + fb * 16 + l15] =
          __float2bfloat16(acc[fb][r] * lr[r]);
    }
}

// ---------------- launch ----------------
extern "C" void kernel_launch(void* const* d_in, const int* in_sizes, int n_in,
                              void* d_out, int out_size, void* d_ws, size_t ws_size,
                              hipStream_t stream) {
  (void)in_sizes; (void)n_in; (void)out_size; (void)ws_size;
  constexpr int S = 2048, E = 2048;

  const float* x   = (const float*)d_in[0];
  const float* Wq  = (const float*)d_in[1];
  const float* Wk  = (const float*)d_in[2];
  const float* Wv  = (const float*)d_in[3];
  const float* Wo  = (const float*)d_in[4];
  const float* qw  = (const float*)d_in[5];
  const float* kw  = (const float*)d_in[6];
  const float* Wrq = (const float*)d_in[7];
  const float* Wrk = (const float*)d_in[8];
  const float* gsc = (const float*)d_in[9];
  float* out = (float*)d_out;

  char* ws = (char*)d_ws;
  size_t off = 0;
  auto alloc = [&](size_t bytes) -> void* {
    void* p = ws + off;
    off += (bytes + 255) & ~(size_t)255;
    return p;
  };
  __hip_bfloat16* xb   = (__hip_bfloat16*)alloc((size_t)S * E * 2);
  __hip_bfloat16* Wall = (__hip_bfloat16*)alloc((size_t)3840 * E * 2);
  __hip_bfloat16* Wob  = (__hip_bfloat16*)alloc((size_t)E * E * 2);
  __hip_bfloat16* qnb  = (__hip_bfloat16*)alloc((size_t)16 * S * 128 * 2);
  __hip_bfloat16* knb  = (__hip_bfloat16*)alloc((size_t)4 * S * 128 * 2);
  __hip_bfloat16* vtb  = (__hip_bfloat16*)alloc((size_t)4 * 128 * S * 2);
  __hip_bfloat16* rqb  = (__hip_bfloat16*)alloc((size_t)12 * S * 32 * 2);
  __hip_bfloat16* rkb  = (__hip_bfloat16*)alloc((size_t)12 * S * 32 * 2);
  float* C1            = (float*)alloc((size_t)S * 3840 * 4);
  __hip_bfloat16* ao   = (__hip_bfloat16*)C1;  // overlay: C1 dead after attn inputs built

  CastArgs ca;
  ca.seg[0] = {x,   xb,                      (int)((size_t)S * E / 4)};
  ca.seg[1] = {Wq,  Wall,                    (int)((size_t)E * E / 4)};
  ca.seg[2] = {Wk,  Wall + (size_t)2048 * E, (int)((size_t)512 * E / 4)};
  ca.seg[3] = {Wv,  Wall + (size_t)2560 * E, (int)((size_t)512 * E / 4)};
  ca.seg[4] = {Wrq, Wall + (size_t)3072 * E, (int)((size_t)384 * E / 4)};
  ca.seg[5] = {Wrk, Wall + (size_t)3456 * E, (int)((size_t)384 * E / 4)};
  ca.seg[6] = {Wo,  Wob,                     (int)((size_t)E * E / 4)};
  ca.tot4 = 0;
  for (int i = 0; i < 7; ++i) ca.tot4 += ca.seg[i].n4;
  cast_all<<<dim3(2048), dim3(256), 0, stream>>>(ca);

  gemm_bt<<<dim3(30, 32), dim3(256), 0, stream>>>(xb, Wall, C1, 3840, E);
  postproc<<<dim3(2048), dim3(256), 0, stream>>>(C1, qw, kw, qnb, knb, rqb, rkb);
  transpose_v<<<dim3(256), dim3(256), 0, stream>>>(C1, vtb);
  attn_kernel<<<dim3(512), dim3(256), 0, stream>>>(qnb, knb, vtb, rqb, rkb, gsc, ao);
  gemm_bt<<<dim3(16, 32), dim3(256), 0, stream>>>(ao, Wob, out, E, E);
}